// Round 2
// baseline (1128.283 us; speedup 1.0000x reference)
//
#include <hip/hip_runtime.h>
#include <math.h>

// approxmatch EMD (Fan et al.) — b=8, n=m=2048, f32.
// Single persistent kernel, 512 blocks (2/CU), 64 blocks per batch.
// Per level t (k_t = level*log2e):
//   A (rows): f_i = remainL_i / (1e-9 + sum_j exp2(k*d2)*R_j)
//   B (cols): s_j = sum_i f_i*exp2(k*d2); colsum=R_j*s_j;
//             rr = min(R_j/(1e-9+colsum),1); c_j = R_j*rr;
//             R_j = max(R_j - colsum*rr, 0)
//   C (rows): t_i = sum_j c_j*e; u_i = sum_j c_j*e*sqrt(d2);
//             remainL_i = max(remainL_i - f_i*t_i, 0); cost_i += f_i*u_i
// C_t and A_{t+1} fused (shared d2). Row/col scalar state lives in registers;
// points live in LDS for the whole kernel; only 8KB weights re-staged/phase.
// Cross-block sync: per-batch monotone atomic barrier (counters zeroed by
// k_init every call -> deterministic, graph-replay safe).

#define NPTS 2048
#define NBATCH 8
#define BPB 64                    // blocks per batch
#define ROWS_PB (NPTS / BPB)      // 32 rows (and cols) per block
#define RPW 8                     // rows per wave (4 waves * 8 = 32)
#define BLOCK 256
#define L2E 1.4426950408889634f

__device__ __forceinline__ float xreduce(float v) {
#pragma unroll
    for (int off = 1; off < 64; off <<= 1)
        v += __shfl_xor(v, off, 64);
    return v;  // all lanes hold the sum
}

__device__ __forceinline__ void batch_barrier(unsigned* cnt, unsigned target) {
    __syncthreads();
    if (threadIdx.x == 0) {
        __threadfence();  // release: publish this block's global writes
        __hip_atomic_fetch_add(cnt, 1u, __ATOMIC_ACQ_REL, __HIP_MEMORY_SCOPE_AGENT);
        while (__hip_atomic_load(cnt, __ATOMIC_ACQUIRE, __HIP_MEMORY_SCOPE_AGENT) < target)
            __builtin_amdgcn_s_sleep(1);
        __threadfence();  // acquire: see other blocks' writes
    }
    __syncthreads();
}

__global__ void k_init(float* remR, unsigned* counters, float multiR, int bm) {
    int i = blockIdx.x * blockDim.x + threadIdx.x;
    if (i < bm) remR[i] = multiR;
    if (blockIdx.x == 0 && threadIdx.x < NBATCH * 32) counters[threadIdx.x] = 0u;
}

__global__ __launch_bounds__(BLOCK, 2) void k_emd(
    const float* __restrict__ xyz1, const float* __restrict__ xyz2,
    float* __restrict__ f_g, float* __restrict__ c_g,
    float* __restrict__ remR_g, float* __restrict__ costrow_g,
    float* __restrict__ out, unsigned* __restrict__ counters,
    float multiL, float multiR)
{
    __shared__ float4 sP2[NPTS];              // xyz2 points; .w = row-phase weight
    __shared__ float sx1[NPTS], sy1[NPTS], sz1[NPTS];  // xyz1 points
    __shared__ float sWa[NPTS];               // col-phase weight / CA second weight
    // total LDS = 32768 + 24576 + 8192 = 65536 B -> 2 blocks/CU

    const int batch = blockIdx.x / BPB;
    const int blk   = blockIdx.x % BPB;
    const int tid   = threadIdx.x;
    const int wave  = tid >> 6, lane = tid & 63;

    const float* g1 = xyz1 + (size_t)batch * NPTS * 3;
    const float* g2 = xyz2 + (size_t)batch * NPTS * 3;
    float* fB    = f_g       + (size_t)batch * NPTS;
    float* cB    = c_g       + (size_t)batch * NPTS;
    float* rB    = remR_g    + (size_t)batch * NPTS;
    float* costB = costrow_g + (size_t)batch * NPTS;
    unsigned* cnt = counters + batch * 32;    // padded counter per batch

    // ---- one-time point staging ----
    for (int i = tid; i < NPTS; i += BLOCK) {
        const float* p1 = g1 + 3 * i;
        sx1[i] = p1[0]; sy1[i] = p1[1]; sz1[i] = p1[2];
        const float* p2 = g2 + 3 * i;
        sP2[i] = make_float4(p2[0], p2[1], p2[2], 0.f);
    }
    __syncthreads();

    const int r0 = blk * ROWS_PB + wave * RPW;  // this wave's rows AND cols

    float px[RPW], py[RPW], pz[RPW];   // my rows' xyz1
    float cx[RPW], cy[RPW], cz[RPW];   // my cols' xyz2
#pragma unroll
    for (int r = 0; r < RPW; ++r) {
        px[r] = sx1[r0 + r]; py[r] = sy1[r0 + r]; pz[r] = sz1[r0 + r];
        float4 q = sP2[r0 + r];
        cx[r] = q.x; cy[r] = q.y; cz[r] = q.z;
    }
    __syncthreads();  // reg loads done before .w overwrites below

    float remL[RPW], remR[RPW], fi[RPW], cost[RPW];
#pragma unroll
    for (int r = 0; r < RPW; ++r) {
        remL[r] = multiL; remR[r] = multiR; cost[r] = 0.f; fi[r] = 0.f;
    }

    unsigned gen = 0;

    // ---- phase A, level 0 (k = -4^7 * log2e) ----
    {
        const float kk = -16384.0f * L2E;
        for (int j = tid; j < NPTS; j += BLOCK) sP2[j].w = rB[j];
        __syncthreads();
        float acc[RPW];
#pragma unroll
        for (int r = 0; r < RPW; ++r) acc[r] = 0.f;
        for (int j = lane; j < NPTS; j += 64) {
            float4 q = sP2[j];
#pragma unroll
            for (int r = 0; r < RPW; ++r) {
                float dx = px[r] - q.x, dy = py[r] - q.y, dz = pz[r] - q.z;
                float d2 = dx * dx + dy * dy + dz * dz;
                acc[r] += q.w * exp2f(kk * d2);
            }
        }
#pragma unroll
        for (int r = 0; r < RPW; ++r) {
            float s = xreduce(acc[r]);
            fi[r] = remL[r] / (1e-9f + s);
        }
        if (lane == 0) {
#pragma unroll
            for (int r = 0; r < RPW; ++r) fB[r0 + r] = fi[r];
        }
    }
    ++gen; batch_barrier(cnt, BPB * gen);

#pragma unroll 1
    for (int t = 0; t < 10; ++t) {
        const float lvl = (t < 9) ? -exp2f(2.0f * (float)(7 - t)) : 0.f;  // -4^(7-t)
        const float kk  = lvl * L2E;
        const float lvn = (t < 8) ? -exp2f(2.0f * (float)(6 - t)) : 0.f;  // next level
        const float kkn = lvn * L2E;
        const bool  doA = (t < 9);

        // ---- phase B (cols) ----
        for (int i = tid; i < NPTS; i += BLOCK) sWa[i] = fB[i];
        __syncthreads();
        {
            float acc[RPW];
#pragma unroll
            for (int r = 0; r < RPW; ++r) acc[r] = 0.f;
            for (int i = lane; i < NPTS; i += 64) {
                float qx = sx1[i], qy = sy1[i], qz = sz1[i], w = sWa[i];
#pragma unroll
                for (int r = 0; r < RPW; ++r) {
                    float dx = cx[r] - qx, dy = cy[r] - qy, dz = cz[r] - qz;
                    float d2 = dx * dx + dy * dy + dz * dz;
                    acc[r] += w * exp2f(kk * d2);
                }
            }
#pragma unroll
            for (int r = 0; r < RPW; ++r) {
                float s = xreduce(acc[r]);
                float colsum = remR[r] * s;
                float rr = fminf(remR[r] / (1e-9f + colsum), 1.0f);
                float cj = remR[r] * rr;
                remR[r] = fmaxf(remR[r] - colsum * rr, 0.f);
                if (lane == 0) { cB[r0 + r] = cj; rB[r0 + r] = remR[r]; }
            }
        }
        ++gen; batch_barrier(cnt, BPB * gen);

        // ---- phase C (+ fused A for level t+1) ----
        for (int j = tid; j < NPTS; j += BLOCK) sP2[j].w = cB[j];
        if (doA)
            for (int j = tid; j < NPTS; j += BLOCK) sWa[j] = rB[j];
        __syncthreads();
        {
            float aT[RPW], aU[RPW], aA[RPW];
#pragma unroll
            for (int r = 0; r < RPW; ++r) { aT[r] = 0.f; aU[r] = 0.f; aA[r] = 0.f; }
            for (int j = lane; j < NPTS; j += 64) {
                float4 q = sP2[j];
                float wr = sWa[j];
#pragma unroll
                for (int r = 0; r < RPW; ++r) {
                    float dx = px[r] - q.x, dy = py[r] - q.y, dz = pz[r] - q.z;
                    float d2 = dx * dx + dy * dy + dz * dz;
                    float e = q.w * exp2f(kk * d2);
                    aT[r] += e;
                    aU[r] += e * sqrtf(fmaxf(d2, 1e-30f));
                    if (doA) aA[r] += wr * exp2f(kkn * d2);
                }
            }
#pragma unroll
            for (int r = 0; r < RPW; ++r) {
                float tt = xreduce(aT[r]);
                float uu = xreduce(aU[r]);
                remL[r] = fmaxf(remL[r] - fi[r] * tt, 0.f);
                cost[r] += fi[r] * uu;
                if (doA) {
                    float aa = xreduce(aA[r]);
                    fi[r] = remL[r] / (1e-9f + aa);
                }
            }
            if (doA && lane == 0) {
#pragma unroll
                for (int r = 0; r < RPW; ++r) fB[r0 + r] = fi[r];
            }
        }
        ++gen; batch_barrier(cnt, BPB * gen);
    }

    // ---- final cost reduction ----
    if (lane == 0) {
#pragma unroll
        for (int r = 0; r < RPW; ++r) costB[r0 + r] = cost[r];
    }
    ++gen; batch_barrier(cnt, BPB * gen);
    if (blk == 0) {
        float s = 0.f;
        for (int i = tid; i < NPTS; i += BLOCK) s += costB[i];
        s = xreduce(s);
        if (lane == 0) sWa[wave] = s;
        __syncthreads();
        if (tid == 0) out[batch] = sWa[0] + sWa[1] + sWa[2] + sWa[3];
    }
}

extern "C" void kernel_launch(void* const* d_in, const int* in_sizes, int n_in,
                              void* d_out, int out_size, void* d_ws, size_t ws_size,
                              hipStream_t stream) {
    const float* xyz1 = (const float*)d_in[0];
    const float* xyz2 = (const float*)d_in[1];
    float* out = (float*)d_out;
    const int b = out_size;                 // 8
    const int n = in_sizes[0] / (3 * b);    // 2048
    const int m = in_sizes[1] / (3 * b);    // 2048
    const int bn = b * n, bm = b * m;

    unsigned* counters = (unsigned*)d_ws;            // NBATCH*32 padded
    float* base    = (float*)d_ws + 256;
    float* remR    = base;                           // bm
    float* f       = remR + bm;                      // bn
    float* c       = f + bn;                         // bm
    float* costrow = c + bm;                         // bn

    const float multiL = (float)((m / n > 1) ? (m / n) : 1);
    const float multiR = (float)((n / m > 1) ? (n / m) : 1);

    k_init<<<dim3((bm + BLOCK - 1) / BLOCK), dim3(BLOCK), 0, stream>>>(
        remR, counters, multiR, bm);
    k_emd<<<dim3(b * BPB), dim3(BLOCK), 0, stream>>>(
        xyz1, xyz2, f, c, remR, costrow, out, counters, multiL, multiR);
}

// Round 3
// 383.685 us; speedup vs baseline: 2.9406x; 2.9406x over previous
//
#include <hip/hip_runtime.h>
#include <math.h>

// approxmatch EMD (Fan et al.) — b=8, n=m=2048, f32. Multi-kernel, no
// global barriers. 23 dispatches:
//   prep | A0 | 10 x { B_t ; CA_t (C_t fused with A_{t+1}) } | cost
// Per level t (kk = level*log2e):
//   A: f_i = remL_i / (1e-9 + sum_j exp2(kk*d2)*R_j)
//   B: s_j = sum_i f_i*exp2(kk*d2); colsum=R_j*s_j;
//      rr=min(R_j/(1e-9+colsum),1); c_j=R_j*rr; R_j=max(R_j-colsum*rr,0)
//   C: t_i=sum_j c_j*e; u_i=sum_j c_j*e*sqrt(d2);
//      remL_i=max(remL_i-f_i*t_i,0); cost_i+=f_i*u_i
// Points packed to float4 once (prep); LDS holds SoA (conflict-free b32
// reads). For t<8 level_t==4*level_{t+1} exactly, so CA computes
// e1=exp2(kkA*d2) and uses e1^4 for the C weight (one transcendental).

#define NPTS 2048
#define BLOCK 256
#define RPW 8
#define RPB ((BLOCK / 64) * RPW)   // 32 rows per block
#define L2E 1.4426950408889634f

__device__ __forceinline__ float xreduce(float v) {
#pragma unroll
    for (int off = 1; off < 64; off <<= 1) v += __shfl_xor(v, off, 64);
    return v;
}
__device__ __forceinline__ float fexp2(float x) { return __builtin_amdgcn_exp2f(x); }
__device__ __forceinline__ float fsqrt(float x) { return __builtin_amdgcn_sqrtf(x); }

__global__ void k_prep(const float* __restrict__ xyz1, const float* __restrict__ xyz2,
                       float4* __restrict__ p1w, float4* __restrict__ p2w,
                       float* __restrict__ remL, float* __restrict__ remR,
                       float* __restrict__ costrow, int bn, int bm,
                       float multiL, float multiR) {
    int i = blockIdx.x * BLOCK + threadIdx.x;
    if (i < bn) {
        const float* p = xyz1 + 3 * (size_t)i;
        p1w[i] = make_float4(p[0], p[1], p[2], 0.f);
        remL[i] = multiL; costrow[i] = 0.f;
    }
    if (i < bm) {
        const float* p = xyz2 + 3 * (size_t)i;
        p2w[i] = make_float4(p[0], p[1], p[2], 0.f);
        remR[i] = multiR;
    }
}

// rows pass, level 0 only (remL == multiL everywhere)
__global__ __launch_bounds__(BLOCK) void k_A(
    const float4* __restrict__ p1w, const float4* __restrict__ p2w,
    const float* __restrict__ remR, float* __restrict__ f_g,
    float kk, float multiL) {
    __shared__ float sx[NPTS], sy[NPTS], sz[NPTS], sw[NPTS];
    const int row0 = blockIdx.x * RPB;
    const int batch = row0 >> 11;
    const float4* P2 = p2w + ((size_t)batch << 11);
    const float* R = remR + ((size_t)batch << 11);
    for (int j = threadIdx.x; j < NPTS; j += BLOCK) {
        float4 q = P2[j]; sx[j] = q.x; sy[j] = q.y; sz[j] = q.z; sw[j] = R[j];
    }
    __syncthreads();
    const int lane = threadIdx.x & 63;
    const int r0 = row0 + (threadIdx.x >> 6) * RPW;
    float px[RPW], py[RPW], pz[RPW], acc[RPW];
#pragma unroll
    for (int r = 0; r < RPW; ++r) {
        float4 q = p1w[r0 + r];
        px[r] = q.x; py[r] = q.y; pz[r] = q.z; acc[r] = 0.f;
    }
    for (int j = lane; j < NPTS; j += 64) {
        float qx = sx[j], qy = sy[j], qz = sz[j], w = sw[j];
#pragma unroll
        for (int r = 0; r < RPW; ++r) {
            float dx = px[r] - qx, dy = py[r] - qy, dz = pz[r] - qz;
            float d2 = dx * dx + dy * dy + dz * dz;
            acc[r] += w * fexp2(kk * d2);
        }
    }
#pragma unroll
    for (int r = 0; r < RPW; ++r) {
        float s = xreduce(acc[r]);
        if (lane == 0) f_g[r0 + r] = multiL / (1e-9f + s);
    }
}

// cols pass
__global__ __launch_bounds__(BLOCK) void k_B(
    const float4* __restrict__ p1w, const float4* __restrict__ p2w,
    const float* __restrict__ f_g, float* __restrict__ remR,
    float* __restrict__ c_g, float kk) {
    __shared__ float sx[NPTS], sy[NPTS], sz[NPTS], sw[NPTS];
    const int col0 = blockIdx.x * RPB;
    const int batch = col0 >> 11;
    const float4* P1 = p1w + ((size_t)batch << 11);
    const float* F = f_g + ((size_t)batch << 11);
    for (int i = threadIdx.x; i < NPTS; i += BLOCK) {
        float4 q = P1[i]; sx[i] = q.x; sy[i] = q.y; sz[i] = q.z; sw[i] = F[i];
    }
    __syncthreads();
    const int lane = threadIdx.x & 63;
    const int c0 = col0 + (threadIdx.x >> 6) * RPW;
    float px[RPW], py[RPW], pz[RPW], acc[RPW];
#pragma unroll
    for (int r = 0; r < RPW; ++r) {
        float4 q = p2w[c0 + r];
        px[r] = q.x; py[r] = q.y; pz[r] = q.z; acc[r] = 0.f;
    }
    for (int i = lane; i < NPTS; i += 64) {
        float qx = sx[i], qy = sy[i], qz = sz[i], w = sw[i];
#pragma unroll
        for (int r = 0; r < RPW; ++r) {
            float dx = px[r] - qx, dy = py[r] - qy, dz = pz[r] - qz;
            float d2 = dx * dx + dy * dy + dz * dz;
            acc[r] += w * fexp2(kk * d2);
        }
    }
#pragma unroll
    for (int r = 0; r < RPW; ++r) {
        float s = xreduce(acc[r]);
        if (lane == 0) {
            int gj = c0 + r;
            float R = remR[gj];
            float colsum = R * s;
            float rr = fminf(R / (1e-9f + colsum), 1.0f);
            c_g[gj] = R * rr;
            remR[gj] = fmaxf(R - colsum * rr, 0.f);
        }
    }
}

// rows pass: C_t fused with A_{t+1}.
// MODE 0: C only (t=9). MODE 1: kk==4*kkA, C weight = e1^4 (t<8).
// MODE 2: A at level 0 (t=8): aA += remR.
template <int MODE>
__global__ __launch_bounds__(BLOCK) void k_CA(
    const float4* __restrict__ p1w, const float4* __restrict__ p2w,
    float* __restrict__ f_g, const float* __restrict__ c_g,
    const float* __restrict__ remR, float* __restrict__ remL,
    float* __restrict__ costrow, float kk, float kkA) {
    __shared__ float sx[NPTS], sy[NPTS], sz[NPTS], sc[NPTS], sr[NPTS];
    const int row0 = blockIdx.x * RPB;
    const int batch = row0 >> 11;
    const float4* P2 = p2w + ((size_t)batch << 11);
    const float* C = c_g + ((size_t)batch << 11);
    const float* R = remR + ((size_t)batch << 11);
    for (int j = threadIdx.x; j < NPTS; j += BLOCK) {
        float4 q = P2[j]; sx[j] = q.x; sy[j] = q.y; sz[j] = q.z; sc[j] = C[j];
        if (MODE) sr[j] = R[j];
    }
    __syncthreads();
    const int lane = threadIdx.x & 63;
    const int r0 = row0 + (threadIdx.x >> 6) * RPW;
    float px[RPW], py[RPW], pz[RPW], aT[RPW], aU[RPW], aA[RPW];
#pragma unroll
    for (int r = 0; r < RPW; ++r) {
        float4 q = p1w[r0 + r];
        px[r] = q.x; py[r] = q.y; pz[r] = q.z;
        aT[r] = 0.f; aU[r] = 0.f; aA[r] = 0.f;
    }
    for (int j = lane; j < NPTS; j += 64) {
        float qx = sx[j], qy = sy[j], qz = sz[j], cw = sc[j];
        float rw = MODE ? sr[j] : 0.f;
#pragma unroll
        for (int r = 0; r < RPW; ++r) {
            float dx = px[r] - qx, dy = py[r] - qy, dz = pz[r] - qz;
            float d2 = dx * dx + dy * dy + dz * dz;
            float e1, e4;
            if (MODE == 1) { e1 = fexp2(kkA * d2); float e2 = e1 * e1; e4 = e2 * e2; }
            else           { e4 = fexp2(kk * d2); e1 = 1.f; }
            float eC = cw * e4;
            aT[r] += eC;
            aU[r] += eC * fsqrt(fmaxf(d2, 1e-30f));
            if (MODE == 1) aA[r] += rw * e1;
            else if (MODE == 2) aA[r] += rw;
        }
    }
#pragma unroll
    for (int r = 0; r < RPW; ++r) {
        float tt = xreduce(aT[r]);
        float uu = xreduce(aU[r]);
        float aa = MODE ? xreduce(aA[r]) : 0.f;
        if (lane == 0) {
            int gi = r0 + r;
            float fi = f_g[gi];
            float rl = fmaxf(remL[gi] - fi * tt, 0.f);
            costrow[gi] += fi * uu;
            remL[gi] = rl;
            if (MODE) f_g[gi] = rl / (1e-9f + aa);
        }
    }
}

__global__ void k_cost(const float* __restrict__ costrow,
                       float* __restrict__ out, int n) {
    __shared__ float wsum[BLOCK / 64];
    const float* cr = costrow + (size_t)blockIdx.x * n;
    float s = 0.f;
    for (int i = threadIdx.x; i < n; i += BLOCK) s += cr[i];
    s = xreduce(s);
    int wave = threadIdx.x >> 6, lane = threadIdx.x & 63;
    if (lane == 0) wsum[wave] = s;
    __syncthreads();
    if (threadIdx.x == 0) {
        float t = 0.f;
#pragma unroll
        for (int w = 0; w < BLOCK / 64; ++w) t += wsum[w];
        out[blockIdx.x] = t;
    }
}

extern "C" void kernel_launch(void* const* d_in, const int* in_sizes, int n_in,
                              void* d_out, int out_size, void* d_ws, size_t ws_size,
                              hipStream_t stream) {
    const float* xyz1 = (const float*)d_in[0];
    const float* xyz2 = (const float*)d_in[1];
    float* out = (float*)d_out;
    const int b = out_size;                 // 8
    const int n = in_sizes[0] / (3 * b);    // 2048
    const int m = in_sizes[1] / (3 * b);    // 2048
    const int bn = b * n, bm = b * m;

    float4* p1w = (float4*)d_ws;            // bn
    float4* p2w = p1w + bn;                 // bm
    float* remL    = (float*)(p2w + bm);    // bn
    float* remR    = remL + bn;             // bm
    float* f       = remR + bm;             // bn
    float* c       = f + bn;                // bm
    float* costrow = c + bm;                // bn

    const float multiL = (float)((m / n > 1) ? (m / n) : 1);
    const float multiR = (float)((n / m > 1) ? (n / m) : 1);

    const int initN = bn > bm ? bn : bm;
    k_prep<<<dim3((initN + BLOCK - 1) / BLOCK), dim3(BLOCK), 0, stream>>>(
        xyz1, xyz2, p1w, p2w, remL, remR, costrow, bn, bm, multiL, multiR);

    dim3 g(bn / RPB), blk(BLOCK);
    const float kk0 = -16384.f * L2E;       // level -4^7
    k_A<<<g, blk, 0, stream>>>(p1w, p2w, remR, f, kk0, multiL);

    for (int t = 0; t < 10; ++t) {
        const float lvl = (t < 9) ? -exp2f(2.f * (float)(7 - t)) : 0.f;  // -4^(7-t)
        const float kk = lvl * L2E;
        const float kkA = kk * 0.25f;       // next level's kk (t<8)
        k_B<<<g, blk, 0, stream>>>(p1w, p2w, f, remR, c, kk);
        if (t < 8)
            k_CA<1><<<g, blk, 0, stream>>>(p1w, p2w, f, c, remR, remL, costrow, kk, kkA);
        else if (t == 8)
            k_CA<2><<<g, blk, 0, stream>>>(p1w, p2w, f, c, remR, remL, costrow, kk, 0.f);
        else
            k_CA<0><<<g, blk, 0, stream>>>(p1w, p2w, f, c, remR, remL, costrow, kk, 0.f);
    }
    k_cost<<<dim3(b), blk, 0, stream>>>(costrow, out, n);
}

// Round 4
// 369.949 us; speedup vs baseline: 3.0498x; 1.0371x over previous
//
#include <hip/hip_runtime.h>
#include <math.h>

// approxmatch EMD (Fan et al.) — b=8, n=m=2048, f32. Multi-kernel, no
// global barriers. 23 dispatches:
//   prep | A0 | 10 x { B_t ; CA_t (C_t fused with A_{t+1}) } | cost
// Per level t (kk = level*log2e):
//   A: f_i = remL_i / (1e-9 + sum_j exp2(kk*d2)*R_j)
//   B: s_j = sum_i f_i*exp2(kk*d2); colsum=R_j*s_j;
//      rr=min(R_j/(1e-9+colsum),1); c_j=R_j*rr; R_j=max(R_j-colsum*rr,0)
//   C: t_i=sum_j c_j*e; u_i=sum_j c_j*e*sqrt(d2);
//      remL_i=max(remL_i-f_i*t_i,0); cost_i+=f_i*u_i
// Points packed to float4 once (prep); LDS holds SoA (conflict-free b32
// reads). For t<8 level_t==4*level_{t+1} exactly, so CA computes
// e1=exp2(kkA*d2) and uses e1^4 for the C weight (one transcendental).
// R4: RPW=4 -> 1024 blocks (4/CU, 4 waves/SIMD) for latency hiding;
// k_A uses remR==multiR constant (no weight staging).

#define NPTS 2048
#define BLOCK 256
#define RPW 4
#define RPB ((BLOCK / 64) * RPW)   // 16 rows per block
#define L2E 1.4426950408889634f

__device__ __forceinline__ float xreduce(float v) {
#pragma unroll
    for (int off = 1; off < 64; off <<= 1) v += __shfl_xor(v, off, 64);
    return v;
}
__device__ __forceinline__ float fexp2(float x) { return __builtin_amdgcn_exp2f(x); }
__device__ __forceinline__ float fsqrt(float x) { return __builtin_amdgcn_sqrtf(x); }

__global__ void k_prep(const float* __restrict__ xyz1, const float* __restrict__ xyz2,
                       float4* __restrict__ p1w, float4* __restrict__ p2w,
                       float* __restrict__ remL, float* __restrict__ remR,
                       float* __restrict__ costrow, int bn, int bm,
                       float multiL, float multiR) {
    int i = blockIdx.x * BLOCK + threadIdx.x;
    if (i < bn) {
        const float* p = xyz1 + 3 * (size_t)i;
        p1w[i] = make_float4(p[0], p[1], p[2], 0.f);
        remL[i] = multiL; costrow[i] = 0.f;
    }
    if (i < bm) {
        const float* p = xyz2 + 3 * (size_t)i;
        p2w[i] = make_float4(p[0], p[1], p[2], 0.f);
        remR[i] = multiR;
    }
}

// rows pass, level 0 only (remL==multiL, remR==multiR everywhere)
__global__ __launch_bounds__(BLOCK) void k_A(
    const float4* __restrict__ p1w, const float4* __restrict__ p2w,
    float* __restrict__ f_g, float kk, float multiL, float multiR) {
    __shared__ float sx[NPTS], sy[NPTS], sz[NPTS];
    const int row0 = blockIdx.x * RPB;
    const int batch = row0 >> 11;
    const float4* P2 = p2w + ((size_t)batch << 11);
    for (int j = threadIdx.x; j < NPTS; j += BLOCK) {
        float4 q = P2[j]; sx[j] = q.x; sy[j] = q.y; sz[j] = q.z;
    }
    __syncthreads();
    const int lane = threadIdx.x & 63;
    const int r0 = row0 + (threadIdx.x >> 6) * RPW;
    float px[RPW], py[RPW], pz[RPW], acc[RPW];
#pragma unroll
    for (int r = 0; r < RPW; ++r) {
        float4 q = p1w[r0 + r];
        px[r] = q.x; py[r] = q.y; pz[r] = q.z; acc[r] = 0.f;
    }
    for (int j = lane; j < NPTS; j += 64) {
        float qx = sx[j], qy = sy[j], qz = sz[j];
#pragma unroll
        for (int r = 0; r < RPW; ++r) {
            float dx = px[r] - qx, dy = py[r] - qy, dz = pz[r] - qz;
            float d2 = dx * dx + dy * dy + dz * dz;
            acc[r] += fexp2(kk * d2);
        }
    }
#pragma unroll
    for (int r = 0; r < RPW; ++r) {
        float s = multiR * xreduce(acc[r]);
        if (lane == 0) f_g[r0 + r] = multiL / (1e-9f + s);
    }
}

// cols pass
__global__ __launch_bounds__(BLOCK) void k_B(
    const float4* __restrict__ p1w, const float4* __restrict__ p2w,
    const float* __restrict__ f_g, float* __restrict__ remR,
    float* __restrict__ c_g, float kk) {
    __shared__ float sx[NPTS], sy[NPTS], sz[NPTS], sw[NPTS];
    const int col0 = blockIdx.x * RPB;
    const int batch = col0 >> 11;
    const float4* P1 = p1w + ((size_t)batch << 11);
    const float* F = f_g + ((size_t)batch << 11);
    for (int i = threadIdx.x; i < NPTS; i += BLOCK) {
        float4 q = P1[i]; sx[i] = q.x; sy[i] = q.y; sz[i] = q.z; sw[i] = F[i];
    }
    __syncthreads();
    const int lane = threadIdx.x & 63;
    const int c0 = col0 + (threadIdx.x >> 6) * RPW;
    float px[RPW], py[RPW], pz[RPW], acc[RPW];
#pragma unroll
    for (int r = 0; r < RPW; ++r) {
        float4 q = p2w[c0 + r];
        px[r] = q.x; py[r] = q.y; pz[r] = q.z; acc[r] = 0.f;
    }
    for (int i = lane; i < NPTS; i += 64) {
        float qx = sx[i], qy = sy[i], qz = sz[i], w = sw[i];
#pragma unroll
        for (int r = 0; r < RPW; ++r) {
            float dx = px[r] - qx, dy = py[r] - qy, dz = pz[r] - qz;
            float d2 = dx * dx + dy * dy + dz * dz;
            acc[r] += w * fexp2(kk * d2);
        }
    }
#pragma unroll
    for (int r = 0; r < RPW; ++r) {
        float s = xreduce(acc[r]);
        if (lane == 0) {
            int gj = c0 + r;
            float R = remR[gj];
            float colsum = R * s;
            float rr = fminf(R / (1e-9f + colsum), 1.0f);
            c_g[gj] = R * rr;
            remR[gj] = fmaxf(R - colsum * rr, 0.f);
        }
    }
}

// rows pass: C_t fused with A_{t+1}.
// MODE 0: C only (t=9). MODE 1: kk==4*kkA, C weight = e1^4 (t<8).
// MODE 2: A at level 0 (t=8): aA += remR.
template <int MODE>
__global__ __launch_bounds__(BLOCK) void k_CA(
    const float4* __restrict__ p1w, const float4* __restrict__ p2w,
    float* __restrict__ f_g, const float* __restrict__ c_g,
    const float* __restrict__ remR, float* __restrict__ remL,
    float* __restrict__ costrow, float kk, float kkA) {
    __shared__ float sx[NPTS], sy[NPTS], sz[NPTS], sc[NPTS], sr[NPTS];
    const int row0 = blockIdx.x * RPB;
    const int batch = row0 >> 11;
    const float4* P2 = p2w + ((size_t)batch << 11);
    const float* C = c_g + ((size_t)batch << 11);
    const float* R = remR + ((size_t)batch << 11);
    for (int j = threadIdx.x; j < NPTS; j += BLOCK) {
        float4 q = P2[j]; sx[j] = q.x; sy[j] = q.y; sz[j] = q.z; sc[j] = C[j];
        if (MODE) sr[j] = R[j];
    }
    __syncthreads();
    const int lane = threadIdx.x & 63;
    const int r0 = row0 + (threadIdx.x >> 6) * RPW;
    float px[RPW], py[RPW], pz[RPW], aT[RPW], aU[RPW], aA[RPW];
#pragma unroll
    for (int r = 0; r < RPW; ++r) {
        float4 q = p1w[r0 + r];
        px[r] = q.x; py[r] = q.y; pz[r] = q.z;
        aT[r] = 0.f; aU[r] = 0.f; aA[r] = 0.f;
    }
    for (int j = lane; j < NPTS; j += 64) {
        float qx = sx[j], qy = sy[j], qz = sz[j], cw = sc[j];
        float rw = MODE ? sr[j] : 0.f;
#pragma unroll
        for (int r = 0; r < RPW; ++r) {
            float dx = px[r] - qx, dy = py[r] - qy, dz = pz[r] - qz;
            float d2 = dx * dx + dy * dy + dz * dz;
            float e1, e4;
            if (MODE == 1) { e1 = fexp2(kkA * d2); float e2 = e1 * e1; e4 = e2 * e2; }
            else           { e4 = fexp2(kk * d2); e1 = 1.f; }
            float eC = cw * e4;
            aT[r] += eC;
            aU[r] += eC * fsqrt(fmaxf(d2, 1e-30f));
            if (MODE == 1) aA[r] += rw * e1;
            else if (MODE == 2) aA[r] += rw;
        }
    }
#pragma unroll
    for (int r = 0; r < RPW; ++r) {
        float tt = xreduce(aT[r]);
        float uu = xreduce(aU[r]);
        float aa = MODE ? xreduce(aA[r]) : 0.f;
        if (lane == 0) {
            int gi = r0 + r;
            float fi = f_g[gi];
            float rl = fmaxf(remL[gi] - fi * tt, 0.f);
            costrow[gi] += fi * uu;
            remL[gi] = rl;
            if (MODE) f_g[gi] = rl / (1e-9f + aa);
        }
    }
}

__global__ void k_cost(const float* __restrict__ costrow,
                       float* __restrict__ out, int n) {
    __shared__ float wsum[BLOCK / 64];
    const float* cr = costrow + (size_t)blockIdx.x * n;
    float s = 0.f;
    for (int i = threadIdx.x; i < n; i += BLOCK) s += cr[i];
    s = xreduce(s);
    int wave = threadIdx.x >> 6, lane = threadIdx.x & 63;
    if (lane == 0) wsum[wave] = s;
    __syncthreads();
    if (threadIdx.x == 0) {
        float t = 0.f;
#pragma unroll
        for (int w = 0; w < BLOCK / 64; ++w) t += wsum[w];
        out[blockIdx.x] = t;
    }
}

extern "C" void kernel_launch(void* const* d_in, const int* in_sizes, int n_in,
                              void* d_out, int out_size, void* d_ws, size_t ws_size,
                              hipStream_t stream) {
    const float* xyz1 = (const float*)d_in[0];
    const float* xyz2 = (const float*)d_in[1];
    float* out = (float*)d_out;
    const int b = out_size;                 // 8
    const int n = in_sizes[0] / (3 * b);    // 2048
    const int m = in_sizes[1] / (3 * b);    // 2048
    const int bn = b * n, bm = b * m;

    float4* p1w = (float4*)d_ws;            // bn
    float4* p2w = p1w + bn;                 // bm
    float* remL    = (float*)(p2w + bm);    // bn
    float* remR    = remL + bn;             // bm
    float* f       = remR + bm;             // bn
    float* c       = f + bn;                // bm
    float* costrow = c + bm;                // bn

    const float multiL = (float)((m / n > 1) ? (m / n) : 1);
    const float multiR = (float)((n / m > 1) ? (n / m) : 1);

    const int initN = bn > bm ? bn : bm;
    k_prep<<<dim3((initN + BLOCK - 1) / BLOCK), dim3(BLOCK), 0, stream>>>(
        xyz1, xyz2, p1w, p2w, remL, remR, costrow, bn, bm, multiL, multiR);

    dim3 g(bn / RPB), blk(BLOCK);
    const float kk0 = -16384.f * L2E;       // level -4^7
    k_A<<<g, blk, 0, stream>>>(p1w, p2w, f, kk0, multiL, multiR);

    for (int t = 0; t < 10; ++t) {
        const float lvl = (t < 9) ? -exp2f(2.f * (float)(7 - t)) : 0.f;  // -4^(7-t)
        const float kk = lvl * L2E;
        const float kkA = kk * 0.25f;       // next level's kk (t<8)
        k_B<<<g, blk, 0, stream>>>(p1w, p2w, f, remR, c, kk);
        if (t < 8)
            k_CA<1><<<g, blk, 0, stream>>>(p1w, p2w, f, c, remR, remL, costrow, kk, kkA);
        else if (t == 8)
            k_CA<2><<<g, blk, 0, stream>>>(p1w, p2w, f, c, remR, remL, costrow, kk, 0.f);
        else
            k_CA<0><<<g, blk, 0, stream>>>(p1w, p2w, f, c, remR, remL, costrow, kk, 0.f);
    }
    k_cost<<<dim3(b), blk, 0, stream>>>(costrow, out, n);
}

// Round 5
// 327.830 us; speedup vs baseline: 3.4417x; 1.1285x over previous
//
#include <hip/hip_runtime.h>
#include <math.h>

// approxmatch EMD (Fan et al.) — b=8, n=m=2048, f32. Multi-kernel, 22
// dispatches: A0(+pack) | 10 x { B_t ; CA_t } | cost.
// Folded exponent form: kk*d2 = kk|p|^2 + kk|q|^2 - 2kk(p.q) -> per-pair
// body = add + 3fma + exp + fmac. For t<8, level_t = 4*level_{t+1} exactly:
// CA computes e1 = exp2(kkA*d2), C-weight = e1^4 (one transcendental), and
// recovers d2 = (kkA*d2)*inv_kkA (clamped >=0) for sqrt.
//   A: f_i = multiL / (1e-9 + multiR * sum_j e)
//   B: s_j = sum_i f_i e; colsum=R s; rr=min(R/(1e-9+colsum),1); c=R rr;
//      R' = max(R - colsum rr, 0)
//   C: t_i = sum_j c e; u_i = sum_j c e sqrt(d2);
//      remL' = max(remL - f t_i, 0); cost += f u_i;  f' = remL'/(1e-9+sum rw e')

#define NPTS 2048
#define BLOCK 256
#define RPW 4
#define RPB ((BLOCK / 64) * RPW)   // 16 rows per block
#define L2E 1.4426950408889634f

__device__ __forceinline__ float xreduce(float v) {
#pragma unroll
    for (int off = 1; off < 64; off <<= 1) v += __shfl_xor(v, off, 64);
    return v;
}
__device__ __forceinline__ float fexp2(float x) { return __builtin_amdgcn_exp2f(x); }
__device__ __forceinline__ float fsqrt(float x) { return __builtin_amdgcn_sqrtf(x); }

// Level-0 rows pass; also packs this block's 16 rows/cols into float4 arrays.
__global__ __launch_bounds__(BLOCK, 4) void k_A(
    const float* __restrict__ xyz1, const float* __restrict__ xyz2,
    float4* __restrict__ p1w, float4* __restrict__ p2w,
    float* __restrict__ f_g, float kk, float multiL, float multiR)
{
    __shared__ float sx[NPTS], sy[NPTS], sz[NPTS], sb[NPTS];
    const int row0 = blockIdx.x * RPB;
    const int batch = row0 >> 11;
    const int rloc = row0 & 2047;
    const float* g1 = xyz1 + (size_t)batch * NPTS * 3;
    const float* g2 = xyz2 + (size_t)batch * NPTS * 3;
    if (threadIdx.x < RPB) {
        int i = rloc + threadIdx.x;
        p1w[((size_t)batch << 11) + i] = make_float4(g1[3*i], g1[3*i+1], g1[3*i+2], 0.f);
    } else if (threadIdx.x < 2 * RPB) {
        int i = rloc + threadIdx.x - RPB;
        p2w[((size_t)batch << 11) + i] = make_float4(g2[3*i], g2[3*i+1], g2[3*i+2], 0.f);
    }
    for (int j = threadIdx.x; j < NPTS; j += BLOCK) {
        float qx = g2[3*j], qy = g2[3*j+1], qz = g2[3*j+2];
        sx[j] = qx; sy[j] = qy; sz[j] = qz;
        sb[j] = kk * (qx*qx + qy*qy + qz*qz);
    }
    __syncthreads();
    const int lane = threadIdx.x & 63;
    const int r0 = row0 + (threadIdx.x >> 6) * RPW;
    float pxp[RPW], pyp[RPW], pzp[RPW], pa[RPW], acc[RPW];
#pragma unroll
    for (int r = 0; r < RPW; ++r) {
        const float* p = g1 + 3 * ((r0 & 2047) + r);
        float x = p[0], y = p[1], z = p[2];
        pa[r] = kk * (x*x + y*y + z*z);
        pxp[r] = -2.f*kk*x; pyp[r] = -2.f*kk*y; pzp[r] = -2.f*kk*z;
        acc[r] = 0.f;
    }
    for (int j = lane; j < NPTS; j += 64) {
        float qx = sx[j], qy = sy[j], qz = sz[j], qb = sb[j];
#pragma unroll
        for (int r = 0; r < RPW; ++r) {
            float t = pa[r] + qb;
            t = fmaf(pxp[r], qx, fmaf(pyp[r], qy, fmaf(pzp[r], qz, t)));
            acc[r] += fexp2(t);
        }
    }
#pragma unroll
    for (int r = 0; r < RPW; ++r) {
        float s = multiR * xreduce(acc[r]);
        if (lane == 0) f_g[r0 + r] = multiL / (1e-9f + s);
    }
}

// cols pass
template <bool FIRST>
__global__ __launch_bounds__(BLOCK, 4) void k_B(
    const float4* __restrict__ p1w, const float4* __restrict__ p2w,
    const float* __restrict__ f_g, float* __restrict__ remR,
    float* __restrict__ c_g, float kk, float multiR)
{
    __shared__ float sx[NPTS], sy[NPTS], sz[NPTS], sb[NPTS], sf[NPTS];
    const int col0 = blockIdx.x * RPB;
    const int batch = col0 >> 11;
    const float4* P1 = p1w + ((size_t)batch << 11);
    const float* F = f_g + ((size_t)batch << 11);
    for (int i = threadIdx.x; i < NPTS; i += BLOCK) {
        float4 q = P1[i];
        sx[i] = q.x; sy[i] = q.y; sz[i] = q.z;
        sb[i] = kk * (q.x*q.x + q.y*q.y + q.z*q.z);
        sf[i] = F[i];
    }
    __syncthreads();
    const int lane = threadIdx.x & 63;
    const int c0 = col0 + (threadIdx.x >> 6) * RPW;
    float cxp[RPW], cyp[RPW], czp[RPW], ca[RPW], acc[RPW];
#pragma unroll
    for (int r = 0; r < RPW; ++r) {
        float4 q = p2w[c0 + r];
        ca[r] = kk * (q.x*q.x + q.y*q.y + q.z*q.z);
        cxp[r] = -2.f*kk*q.x; cyp[r] = -2.f*kk*q.y; czp[r] = -2.f*kk*q.z;
        acc[r] = 0.f;
    }
    for (int i = lane; i < NPTS; i += 64) {
        float qx = sx[i], qy = sy[i], qz = sz[i], qb = sb[i], w = sf[i];
#pragma unroll
        for (int r = 0; r < RPW; ++r) {
            float t = ca[r] + qb;
            t = fmaf(cxp[r], qx, fmaf(cyp[r], qy, fmaf(czp[r], qz, t)));
            acc[r] = fmaf(w, fexp2(t), acc[r]);
        }
    }
#pragma unroll
    for (int r = 0; r < RPW; ++r) {
        float s = xreduce(acc[r]);
        if (lane == 0) {
            int gj = c0 + r;
            float R = FIRST ? multiR : remR[gj];
            float colsum = R * s;
            float rr = fminf(R / (1e-9f + colsum), 1.0f);
            c_g[gj] = R * rr;
            remR[gj] = fmaxf(R - colsum * rr, 0.f);
        }
    }
}

// rows pass: C_t fused with A_{t+1}.
// MODE 0: t=9 (kk=0): C only, e==1, no transcendental exp.
// MODE 1: t<8: kp=kk/4, C-weight=e1^4, aA += rw*e1.
// MODE 2: t=8: kp=kk, aA-part: next level 0 -> sum of rw (hoisted).
template <int MODE, bool FIRSTC>
__global__ __launch_bounds__(BLOCK, 4) void k_CA(
    const float4* __restrict__ p1w, const float4* __restrict__ p2w,
    float* __restrict__ f_g, const float* __restrict__ c_g,
    const float* __restrict__ remR, float* __restrict__ remL,
    float* __restrict__ costrow, float kp, float invkp, float multiL)
{
    __shared__ float sx[NPTS], sy[NPTS], sz[NPTS], sc[NPTS], sr[NPTS];
    const int row0 = blockIdx.x * RPB;
    const int batch = row0 >> 11;
    const float4* P2 = p2w + ((size_t)batch << 11);
    const float* C = c_g + ((size_t)batch << 11);
    const float* R = remR + ((size_t)batch << 11);
    for (int j = threadIdx.x; j < NPTS; j += BLOCK) {
        float4 q = P2[j];
        sx[j] = q.x; sy[j] = q.y; sz[j] = q.z; sc[j] = C[j];
        if (MODE) sr[j] = R[j];
    }
    __syncthreads();
    const int lane = threadIdx.x & 63;
    const int r0 = row0 + (threadIdx.x >> 6) * RPW;
    float pxp[RPW], pyp[RPW], pzp[RPW], pa[RPW];
    float aT[RPW], aU[RPW], aA[RPW];
    float aAs = 0.f;
#pragma unroll
    for (int r = 0; r < RPW; ++r) {
        float4 q = p1w[r0 + r];
        if (MODE == 0) { pxp[r] = q.x; pyp[r] = q.y; pzp[r] = q.z; pa[r] = 0.f; }
        else {
            pa[r] = kp * (q.x*q.x + q.y*q.y + q.z*q.z);
            pxp[r] = -2.f*kp*q.x; pyp[r] = -2.f*kp*q.y; pzp[r] = -2.f*kp*q.z;
        }
        aT[r] = 0.f; aU[r] = 0.f; aA[r] = 0.f;
    }
    for (int j = lane; j < NPTS; j += 64) {
        float qx = sx[j], qy = sy[j], qz = sz[j], cw = sc[j];
        if (MODE == 0) {
#pragma unroll
            for (int r = 0; r < RPW; ++r) {
                float dx = pxp[r] - qx, dy = pyp[r] - qy, dz = pzp[r] - qz;
                float d2 = fmaf(dx, dx, fmaf(dy, dy, dz * dz));
                aT[r] += cw;
                aU[r] = fmaf(cw, fsqrt(d2), aU[r]);
            }
        } else {
            float qb = kp * fmaf(qx, qx, fmaf(qy, qy, qz * qz));
            float rw = sr[j];
            if (MODE == 2) aAs += rw;
#pragma unroll
            for (int r = 0; r < RPW; ++r) {
                float t = pa[r] + qb;
                t = fmaf(pxp[r], qx, fmaf(pyp[r], qy, fmaf(pzp[r], qz, t)));
                float e1 = fexp2(t);
                float e4;
                if (MODE == 1) { float e2 = e1 * e1; e4 = e2 * e2; } else e4 = e1;
                float d2 = fmaxf(t * invkp, 0.f);   // guard rounding-negative
                float eC = cw * e4;
                aT[r] += eC;
                aU[r] = fmaf(eC, fsqrt(d2), aU[r]);
                if (MODE == 1) aA[r] = fmaf(rw, e1, aA[r]);
            }
        }
    }
    float aas = (MODE == 2) ? xreduce(aAs) : 0.f;
#pragma unroll
    for (int r = 0; r < RPW; ++r) {
        float tt = xreduce(aT[r]);
        float uu = xreduce(aU[r]);
        float aa = (MODE == 1) ? xreduce(aA[r]) : aas;
        if (lane == 0) {
            int gi = r0 + r;
            float fi = f_g[gi];
            float rl0 = FIRSTC ? multiL : remL[gi];
            float rl = fmaxf(rl0 - fi * tt, 0.f);
            float cst = FIRSTC ? 0.f : costrow[gi];
            costrow[gi] = cst + fi * uu;
            remL[gi] = rl;
            if (MODE) f_g[gi] = rl / (1e-9f + aa);
        }
    }
}

__global__ void k_cost(const float* __restrict__ costrow,
                       float* __restrict__ out, int n) {
    __shared__ float wsum[BLOCK / 64];
    const float* cr = costrow + (size_t)blockIdx.x * n;
    float s = 0.f;
    for (int i = threadIdx.x; i < n; i += BLOCK) s += cr[i];
    s = xreduce(s);
    int wave = threadIdx.x >> 6, lane = threadIdx.x & 63;
    if (lane == 0) wsum[wave] = s;
    __syncthreads();
    if (threadIdx.x == 0) {
        float t = 0.f;
#pragma unroll
        for (int w = 0; w < BLOCK / 64; ++w) t += wsum[w];
        out[blockIdx.x] = t;
    }
}

extern "C" void kernel_launch(void* const* d_in, const int* in_sizes, int n_in,
                              void* d_out, int out_size, void* d_ws, size_t ws_size,
                              hipStream_t stream) {
    const float* xyz1 = (const float*)d_in[0];
    const float* xyz2 = (const float*)d_in[1];
    float* out = (float*)d_out;
    const int b = out_size;                 // 8
    const int n = in_sizes[0] / (3 * b);    // 2048
    const int m = in_sizes[1] / (3 * b);    // 2048
    const int bn = b * n, bm = b * m;

    float4* p1w = (float4*)d_ws;            // bn
    float4* p2w = p1w + bn;                 // bm
    float* remL    = (float*)(p2w + bm);    // bn
    float* remR    = remL + bn;             // bm
    float* f       = remR + bm;             // bn
    float* c       = f + bn;                // bm
    float* costrow = c + bm;                // bn

    const float multiL = (float)((m / n > 1) ? (m / n) : 1);
    const float multiR = (float)((n / m > 1) ? (n / m) : 1);

    dim3 g(bn / RPB), blk(BLOCK);
    const float kk0 = -16384.f * L2E;       // level -4^7
    k_A<<<g, blk, 0, stream>>>(xyz1, xyz2, p1w, p2w, f, kk0, multiL, multiR);

    for (int t = 0; t < 10; ++t) {
        const float lvl = (t < 9) ? -exp2f(2.f * (float)(7 - t)) : 0.f;  // -4^(7-t)
        const float kk = lvl * L2E;
        if (t == 0)
            k_B<true><<<g, blk, 0, stream>>>(p1w, p2w, f, remR, c, kk, multiR);
        else
            k_B<false><<<g, blk, 0, stream>>>(p1w, p2w, f, remR, c, kk, multiR);

        if (t == 0) {
            float kp = kk * 0.25f;
            k_CA<1, true><<<g, blk, 0, stream>>>(p1w, p2w, f, c, remR, remL,
                                                 costrow, kp, 1.f / kp, multiL);
        } else if (t < 8) {
            float kp = kk * 0.25f;
            k_CA<1, false><<<g, blk, 0, stream>>>(p1w, p2w, f, c, remR, remL,
                                                  costrow, kp, 1.f / kp, multiL);
        } else if (t == 8) {
            k_CA<2, false><<<g, blk, 0, stream>>>(p1w, p2w, f, c, remR, remL,
                                                  costrow, kk, 1.f / kk, multiL);
        } else {
            k_CA<0, false><<<g, blk, 0, stream>>>(p1w, p2w, f, c, remR, remL,
                                                  costrow, 0.f, 0.f, multiL);
        }
    }
    k_cost<<<dim3(b), blk, 0, stream>>>(costrow, out, n);
}